// Round 7
// baseline (603.516 us; speedup 1.0000x reference)
//
#include <hip/hip_runtime.h>

typedef unsigned short u16;
typedef __attribute__((ext_vector_type(4))) float f32x4;
using bf16x8 = __attribute__((ext_vector_type(8))) short;
typedef __attribute__((ext_vector_type(8))) unsigned short u16x8;
typedef __attribute__((ext_vector_type(4))) unsigned short u16x4;

#define GAS __attribute__((address_space(1)))
#define LAS __attribute__((address_space(3)))

__device__ __forceinline__ float bf2f(u16 u) {
  unsigned v = ((unsigned)u) << 16;
  float f;
  __builtin_memcpy(&f, &v, 4);
  return f;
}
__device__ __forceinline__ u16 f2bf(float f) {
  unsigned u;
  __builtin_memcpy(&u, &f, 4);
  u += 0x7fffu + ((u >> 16) & 1u);
  return (u16)(u >> 16);
}
__device__ __forceinline__ void llds16(const void* g, void* l) {
  __builtin_amdgcn_global_load_lds((const GAS unsigned*)g, (LAS unsigned*)l, 16, 0, 0);
}

// ---------------- router (+ fused x->xb bf16 conversion) ----------------
// 64 tokens/block, wave = H-slice. Router reads every x element exactly once,
// so it also emits xb (bf16) — cvtx_k is gone.
__global__ __launch_bounds__(256) void router_k(const float* __restrict__ x,
    const float* __restrict__ rw, const float* __restrict__ rb,
    int* __restrict__ topk_idx, float* __restrict__ topk_w, int* __restrict__ ib,
    u16* __restrict__ xb) {
  __shared__ float xs[4][32 * 65];    // [wave][h*65 + tok]
  __shared__ float wsm[4][32 * 16];   // [wave][h*16 + e]
  __shared__ float part[4][64 * 17];  // [wave][tok*17 + e]
  __shared__ int cnt[16];
  const int tid = threadIdx.x;
  const int wv = __builtin_amdgcn_readfirstlane(tid >> 6);
  const int lane = tid & 63;
  const int tok0 = blockIdx.x * 64;
  const int rr = lane >> 3;       // row-sub 0..7
  const int c4 = (lane & 7) * 4;  // col within 32-h chunk

  float acc[16];
#pragma unroll
  for (int e = 0; e < 16; ++e) acc[e] = 0.f;

  for (int c = 0; c < 8; ++c) {
    const int hb = wv * 256 + c * 32;
    // stage w chunk (512 contiguous floats)
    {
      f32x4 wa = *(const f32x4*)(rw + hb * 16 + lane * 4);
      f32x4 wb = *(const f32x4*)(rw + hb * 16 + 256 + lane * 4);
      *(f32x4*)&wsm[wv][lane * 4] = wa;
      *(f32x4*)&wsm[wv][256 + lane * 4] = wb;
    }
    // stage x chunk transposed + emit bf16 copy
#pragma unroll
    for (int i = 0; i < 8; ++i) {
      const int row = i * 8 + rr;
      const long gb = (long)(tok0 + row) * 1024 + hb + c4;
      f32x4 v = *(const f32x4*)(x + gb);
      u16x4 b4;
#pragma unroll
      for (int j = 0; j < 4; ++j) {
        xs[wv][(c4 + j) * 65 + row] = v[j];
        b4[j] = f2bf(v[j]);
      }
      *(u16x4*)(xb + gb) = b4;
    }
    __syncthreads();
#pragma unroll
    for (int h = 0; h < 32; ++h) {
      const float xv = xs[wv][h * 65 + lane];
      const float* wrow = &wsm[wv][h * 16];
#pragma unroll
      for (int q = 0; q < 4; ++q) {
        f32x4 w4 = *(const f32x4*)(wrow + q * 4);
#pragma unroll
        for (int e = 0; e < 4; ++e) acc[q * 4 + e] += xv * w4[e];
      }
    }
    __syncthreads();
  }
#pragma unroll
  for (int e = 0; e < 16; ++e) part[wv][lane * 17 + e] = acc[e];
  if (tid < 16) cnt[tid] = 0;
  __syncthreads();
  if (tid < 64) {
    float p[16];
#pragma unroll
    for (int e = 0; e < 16; ++e)
      p[e] = part[0][tid * 17 + e] + part[1][tid * 17 + e] +
             part[2][tid * 17 + e] + part[3][tid * 17 + e] + rb[e];
    float mx = p[0];
#pragma unroll
    for (int e = 1; e < 16; ++e) mx = fmaxf(mx, p[e]);
    float sum = 0.f;
#pragma unroll
    for (int e = 0; e < 16; ++e) { p[e] = __expf(p[e] - mx); sum += p[e]; }
    int i0 = 0; float p0 = p[0];
    for (int e = 1; e < 16; ++e) if (p[e] > p0) { p0 = p[e]; i0 = e; }
    int i1 = -1; float p1 = -1.f;
    for (int e = 0; e < 16; ++e) if (e != i0 && p[e] > p1) { p1 = p[e]; i1 = e; }
    const float inv = 1.f / sum;
    p0 *= inv; p1 *= inv;
    const float d = p0 + p1 + 1e-6f;
    const int t = tok0 + tid;
    topk_idx[t * 2] = i0; topk_idx[t * 2 + 1] = i1;
    topk_w[t * 2] = p0 / d;
    topk_w[t * 2 + 1] = p1 / d;
    if (i0 < 15) atomicAdd(&cnt[i0], 1);
    if (i1 < 15) atomicAdd(&cnt[i1], 1);
  }
  __syncthreads();
  if (tid < 15 && cnt[tid] > 0) atomicAdd(&ib[tid], cnt[tid]);
}

// ib layout: [0..15] counts, [16..31] offsets (offs[15]=total), [32..47] cursors,
//            [48] n_mtiles, [64..] mtile table {expert,row0,row_end,pad}
__global__ void zero_k(int* __restrict__ ib) {
  if (threadIdx.x < 16) ib[threadIdx.x] = 0;
}

__global__ void scan_k(int* __restrict__ ib) {
  if (threadIdx.x != 0 || blockIdx.x != 0) return;
  int off = 0;
  for (int ee = 0; ee < 15; ++ee) { ib[16 + ee] = off; ib[32 + ee] = off; off += ib[ee]; }
  ib[16 + 15] = off;
  int nm = 0;
  for (int ee = 0; ee < 15; ++ee) {
    const int st = ib[16 + ee], en = ib[16 + ee + 1];
    for (int r = st; r < en; r += 128) {
      ib[64 + nm * 4] = ee; ib[64 + nm * 4 + 1] = r; ib[64 + nm * 4 + 2] = en; ++nm;
    }
  }
  ib[48] = nm;
}

// scatter v2: per-block LDS aggregation, 15 global atomics/block
__global__ __launch_bounds__(256) void scatter_k(const int* __restrict__ topk_idx,
                          const float* __restrict__ topk_w,
                          int* __restrict__ ib, int* __restrict__ tok_ids,
                          float* __restrict__ tok_w, int* __restrict__ slot_map) {
  __shared__ int cnt[16], base[16];
  const int tid = threadIdx.x;
  const int j = blockIdx.x * 256 + tid;
  if (tid < 16) cnt[tid] = 0;
  __syncthreads();
  const int e = topk_idx[j];
  int lo = 0;
  if (e < 15) lo = atomicAdd(&cnt[e], 1);
  __syncthreads();
  if (tid < 15 && cnt[tid] > 0) base[tid] = atomicAdd(&ib[32 + tid], cnt[tid]);
  __syncthreads();
  if (e < 15) {
    const int pos = base[e] + lo;
    tok_ids[pos] = j >> 1;
    tok_w[pos] = topk_w[j];
    slot_map[j] = pos;
  } else {
    slot_map[j] = -1;
  }
}

// ------- weight transpose + fp32->bf16: dst[b][c][r] = src[b][r][c] -------
__global__ void transpose_k(const float* __restrict__ src, u16* __restrict__ dst, int R, int C) {
  __shared__ float tile[32][33];
  src += (long)blockIdx.z * R * C;
  dst += (long)blockIdx.z * R * C;
  const int c0 = blockIdx.x * 32, r0 = blockIdx.y * 32;
  const int tx = threadIdx.x & 31, ty = threadIdx.x >> 5;
#pragma unroll
  for (int i = ty; i < 32; i += 8) tile[i][tx] = src[(long)(r0 + i) * C + c0 + tx];
  __syncthreads();
#pragma unroll
  for (int i = ty; i < 32; i += 8) dst[(long)(c0 + i) * R + r0 + tx] = f2bf(tile[tx][i]);
}

// conv_w (I,H,KS) fp32 -> (KS, I, H) bf16
__global__ void convt_k(const float* __restrict__ cw, u16* __restrict__ dst) {
  const int idx = blockIdx.x * 256 + threadIdx.x;
  if (idx >= 3 * 512 * 1024) return;
  const int k = idx >> 19;
  const int rem = idx & 524287;
  const int i = rem >> 10, h = rem & 1023;
  dst[idx] = f2bf(cw[i * 3072 + h * 3 + k]);
}

// ---------------- unified MFMA GEMM, BM=128 ----------------
// Flat grid + XCD-aware remap (T1, round 3: FETCH 381->61MB, verified).
// V!=3 K-loop: 3-buffer depth-2 counted-vmcnt pipeline (round 6, verified).
// LDS chunk swizzle (rule #21): linear gload_lds dest + inverse-swizzled
// GLOBAL source + swizzled read: chunk' = chunk ^ ((row>>1)&3).
// V=0: gathered gate+up, fused silu*up -> inter (128 x 64 out, bf16)
// V=1: expert down (A=inter), fused *tok_w -> Y (128 x 128, bf16)
// V=3: FUSED shared expert up-path: 3 conv K-phases -> acc, + 1 phase
//      (B=Bt1=sup_t) -> acc2; epilogue writes f2bf(silu(conv)*up) to OUT.
//      (replaces old gemm<2>+gemm<3> pair; legacy 2-buffer loop)
// V=4: C = A @ B^T + FUSED final combine: out = C + routed(Y/smap/topw, x)
template<int V>
__global__ __launch_bounds__(256, 2)
void gemm_k(const u16* __restrict__ Abase, const u16* __restrict__ Bt0,
            const u16* __restrict__ Bt1, void* __restrict__ OUTv,
            const int* __restrict__ tbl, const int* __restrict__ nmt,
            const int* __restrict__ tok_ids, const float* __restrict__ tok_w,
            int K, int ldA, int ldOut) {
  __shared__ u16 lds[24576];  // 48 KB: 3 staging buffers of 16 KB (V==3 uses 2)
  u16* OUT = (u16*)OUTv;
  float* OUTF = (float*)OUTv;
  const int tid = threadIdx.x;
  const int wave = tid >> 6, lane = tid & 63;
  const int quad = lane >> 4, l16 = lane & 15;
  const int rA = tid >> 2;           // staging row (and +64)
  const int sub8 = (tid & 3) * 8;    // linear dest chunk (V3 ds_write dest)
  const int sub8s = ((tid & 3) ^ ((tid >> 3) & 3)) * 8;  // swizzled source chunk

  // ---- XCD-aware flat-grid remap (grid size is always a multiple of 8) ----
  constexpr int NYC = (V == 3) ? 4 : 8;  // col-blocks per row-tile
  const int lin = (blockIdx.x & 7) * (gridDim.x >> 3) + (blockIdx.x >> 3);
  const int bx = lin / NYC, by = lin - bx * NYC;

  int e = 0, row0, row_end;
  if constexpr (V <= 1) {
    if (bx >= *nmt) return;
    e = tbl[bx * 4]; row0 = tbl[bx * 4 + 1]; row_end = tbl[bx * 4 + 2];
  } else {
    row0 = bx * 128; row_end = row0 + 128;
  }
  const int n0 = by * ((V == 0) ? 64 : 128);

  f32x4 acc[2][8];
  f32x4 acc2[2][8];  // only live for V==3 (DCE'd otherwise)
#pragma unroll
  for (int i = 0; i < 2; ++i)
#pragma unroll
    for (int j = 0; j < 8; ++j) {
      acc[i][j] = (f32x4){0.f, 0.f, 0.f, 0.f};
      if constexpr (V == 3) acc2[i][j] = (f32x4){0.f, 0.f, 0.f, 0.f};
    }

  // swizzled read chunk: for every A/B row this thread reads, (row>>1)&3 == (l16>>1)&3
  const int swz8 = (((l16 >> 1) & 3) ^ quad) * 8;
  const int aoff0 = (wave * 32 + l16) * 32 + swz8;
  const int aoff1 = aoff0 + 512;
  const int kIters = K / 32;

  if constexpr (V != 3) {
    const u16 *pA0, *pA1, *pB0, *pB1;
    if constexpr (V == 0) {
      const int t0i = tok_ids[min(row0 + rA, row_end - 1)];
      const int t1i = tok_ids[min(row0 + rA + 64, row_end - 1)];
      pA0 = Abase + (long)t0i * 1024 + sub8s;
      pA1 = Abase + (long)t1i * 1024 + sub8s;
      pB0 = Bt0 + ((long)e * 512 + n0 + rA) * 1024 + sub8s;  // gate
      pB1 = Bt1 + ((long)e * 512 + n0 + rA) * 1024 + sub8s;  // up
    } else if constexpr (V == 1) {
      pA0 = Abase + (long)min(row0 + rA, row_end - 1) * 512 + sub8s;
      pA1 = Abase + (long)min(row0 + rA + 64, row_end - 1) * 512 + sub8s;
      pB0 = Bt0 + ((long)e * 1024 + n0 + rA) * 512 + sub8s;
      pB1 = Bt0 + ((long)e * 1024 + n0 + rA + 64) * 512 + sub8s;
    } else {  // V == 4
      pA0 = Abase + (long)(row0 + rA) * ldA + sub8s;
      pA1 = Abase + (long)(row0 + rA + 64) * ldA + sub8s;
      pB0 = Bt0 + (long)(n0 + rA) * K + sub8s;
      pB1 = Bt0 + (long)(n0 + rA + 64) * K + sub8s;
    }
    auto STAGE = [&](int buf) {
      llds16(pA0, &lds[buf + wave * 512]); pA0 += 32;
      llds16(pA1, &lds[buf + 2048 + wave * 512]); pA1 += 32;
      llds16(pB0, &lds[buf + 4096 + wave * 512]); pB0 += 32;
      llds16(pB1, &lds[buf + 6144 + wave * 512]); pB1 += 32;
    };
    // prologue: tiles 0 and 1 in flight
    STAGE(0);
    STAGE(8192);
    int cur = 0, stg = 16384;
    for (int kb = 0; kb < kIters; ++kb) {
      if (kb + 1 < kIters) {
        asm volatile("s_waitcnt vmcnt(4)" ::: "memory");  // tile kb landed
      } else {
        asm volatile("s_waitcnt vmcnt(0)" ::: "memory");  // tail: drain last tile
      }
      __builtin_amdgcn_s_barrier();  // raw: tile kb+1 DMA stays in flight
      if (kb + 2 < kIters) {
        STAGE(stg);  // buffer last read 2 iters ago: reader-free
        stg = (stg == 16384) ? 0 : stg + 8192;
      }
      bf16x8 a0 = *(const bf16x8*)&lds[cur + aoff0];
      bf16x8 a1 = *(const bf16x8*)&lds[cur + aoff1];
      __builtin_amdgcn_s_setprio(1);
#pragma unroll
      for (int nt = 0; nt < 8; ++nt) {
        bf16x8 b = *(const bf16x8*)&lds[cur + 4096 + (nt * 16 + l16) * 32 + swz8];
        acc[0][nt] = __builtin_amdgcn_mfma_f32_16x16x32_bf16(a0, b, acc[0][nt], 0, 0, 0);
        acc[1][nt] = __builtin_amdgcn_mfma_f32_16x16x32_bf16(a1, b, acc[1][nt], 0, 0, 0);
      }
      __builtin_amdgcn_s_setprio(0);
      cur = (cur == 16384) ? 0 : cur + 8192;
    }
    __builtin_amdgcn_s_barrier();  // all waves done with last tile: LDS reusable
  } else {
    // ---- V == 3 fused: conv phases 0..2 -> acc; sup phase -> acc2 ----
    int cur = 0;
    u16x8 va0n, va1n;
    const int bb = row0 >> 12, s0 = row0 & 4095;
    for (int ph = 0; ph < 3; ++ph) {
      const u16 *pA0, *pA1, *pB0, *pB1;
      const int si0 = s0 + ph - 2 + rA;
      const bool zero0 = si0 < 0;
      pA0 = Abase + ((long)bb * 4096 + (si0 < 0 ? 0 : si0)) * 1024 + sub8s;
      pA1 = Abase + ((long)bb * 4096 + (si0 + 64)) * 1024 + sub8s;
      pB0 = Bt0 + (long)ph * 524288 + (long)(n0 + rA) * 1024 + sub8s;
      pB1 = Bt0 + (long)ph * 524288 + (long)(n0 + rA + 64) * 1024 + sub8s;

      va0n = *(const u16x8*)pA0; pA0 += 32;
      va1n = *(const u16x8*)pA1; pA1 += 32;
      if (zero0) va0n = (u16x8){0, 0, 0, 0, 0, 0, 0, 0};
      *(u16x8*)&lds[cur + rA * 32 + sub8] = va0n;
      *(u16x8*)&lds[cur + (rA + 64) * 32 + sub8] = va1n;
      llds16(pB0, &lds[cur + 4096 + wave * 512]); pB0 += 32;
      llds16(pB1, &lds[cur + 6144 + wave * 512]); pB1 += 32;
      __syncthreads();  // k=0 resident

      for (int kb = 0; kb < kIters; ++kb) {
        const int nxt = cur ^ 8192;
        const bool pre = (kb + 1 < kIters);
        if (pre) {
          llds16(pB0, &lds[nxt + 4096 + wave * 512]); pB0 += 32;
          llds16(pB1, &lds[nxt + 6144 + wave * 512]); pB1 += 32;
          va0n = *(const u16x8*)pA0; pA0 += 32;
          va1n = *(const u16x8*)pA1; pA1 += 32;
          if (zero0) va0n = (u16x8){0, 0, 0, 0, 0, 0, 0, 0};
        }
        bf16x8 a0 = *(const bf16x8*)&lds[cur + aoff0];
        bf16x8 a1 = *(const bf16x8*)&lds[cur + aoff1];
#pragma unroll
        for (int nt = 0; nt < 8; ++nt) {
          bf16x8 b = *(const bf16x8*)&lds[cur + 4096 + (nt * 16 + l16) * 32 + swz8];
          acc[0][nt] = __builtin_amdgcn_mfma_f32_16x16x32_bf16(a0, b, acc[0][nt], 0, 0, 0);
          acc[1][nt] = __builtin_amdgcn_mfma_f32_16x16x32_bf16(a1, b, acc[1][nt], 0, 0, 0);
        }
        if (pre) {
          *(u16x8*)&lds[nxt + rA * 32 + sub8] = va0n;
          *(u16x8*)&lds[nxt + (rA + 64) * 32 + sub8] = va1n;
        }
        __syncthreads();
        cur = nxt;
      }
    }
    // ---- phase 3: B = sup_t (Bt1), A unshifted; accumulate into acc2 ----
    {
      const u16* pA0 = Abase + ((long)bb * 4096 + s0 + rA) * 1024 + sub8s;
      const u16* pA1 = Abase + ((long)bb * 4096 + s0 + rA + 64) * 1024 + sub8s;
      const u16* pB0 = Bt1 + (long)(n0 + rA) * 1024 + sub8s;
      const u16* pB1 = Bt1 + (long)(n0 + rA + 64) * 1024 + sub8s;

      va0n = *(const u16x8*)pA0; pA0 += 32;
      va1n = *(const u16x8*)pA1; pA1 += 32;
      *(u16x8*)&lds[cur + rA * 32 + sub8] = va0n;
      *(u16x8*)&lds[cur + (rA + 64) * 32 + sub8] = va1n;
      llds16(pB0, &lds[cur + 4096 + wave * 512]); pB0 += 32;
      llds16(pB1, &lds[cur + 6144 + wave * 512]); pB1 += 32;
      __syncthreads();

      for (int kb = 0; kb < kIters; ++kb) {
        const int nxt = cur ^ 8192;
        const bool pre = (kb + 1 < kIters);
        if (pre) {
          llds16(pB0, &lds[nxt + 4096 + wave * 512]); pB0 += 32;
          llds16(pB1, &lds[nxt + 6144 + wave * 512]); pB1 += 32;
          va0n = *(const u16x8*)pA0; pA0 += 32;
          va1n = *(const u16x8*)pA1; pA1 += 32;
        }
        bf16x8 a0 = *(const bf16x8*)&lds[cur + aoff0];
        bf16x8 a1 = *(const bf16x8*)&lds[cur + aoff1];
#pragma unroll
        for (int nt = 0; nt < 8; ++nt) {
          bf16x8 b = *(const bf16x8*)&lds[cur + 4096 + (nt * 16 + l16) * 32 + swz8];
          acc2[0][nt] = __builtin_amdgcn_mfma_f32_16x16x32_bf16(a0, b, acc2[0][nt], 0, 0, 0);
          acc2[1][nt] = __builtin_amdgcn_mfma_f32_16x16x32_bf16(a1, b, acc2[1][nt], 0, 0, 0);
        }
        if (pre) {
          *(u16x8*)&lds[nxt + rA * 32 + sub8] = va0n;
          *(u16x8*)&lds[nxt + (rA + 64) * 32 + sub8] = va1n;
        }
        __syncthreads();
        cur = nxt;
      }
    }
  }

  // ---- epilogue ----
  const int rbase = wave * 32;
  if constexpr (V == 0) {
#pragma unroll
    for (int mt = 0; mt < 2; ++mt)
#pragma unroll
      for (int r = 0; r < 4; ++r) {
        const int row = rbase + mt * 16 + quad * 4 + r;
#pragma unroll
        for (int nt = 0; nt < 4; ++nt) {
          float g = acc[mt][nt][r], u = acc[mt][nt + 4][r];
          float sg = g / (1.f + __expf(-g));
          lds[row * 64 + nt * 16 + l16] = f2bf(sg * u);
        }
      }
    __syncthreads();
#pragma unroll
    for (int i = 0; i < 4; ++i) {
      const int c = i * 256 + tid;
      const int row = c >> 3, s8 = (c & 7) * 8;
      const int slot = row0 + row;
      if (slot < row_end)
        *(u16x8*)(OUT + (long)slot * ldOut + n0 + s8) = *(const u16x8*)&lds[row * 64 + s8];
    }
  } else if constexpr (V == 1) {
#pragma unroll
    for (int mt = 0; mt < 2; ++mt)
#pragma unroll
      for (int r = 0; r < 4; ++r) {
        const int row = rbase + mt * 16 + quad * 4 + r;
        const float wgt = tok_w[min(row0 + row, row_end - 1)];
#pragma unroll
        for (int nt = 0; nt < 8; ++nt)
          lds[row * 128 + nt * 16 + l16] = f2bf(acc[mt][nt][r] * wgt);
      }
    __syncthreads();
#pragma unroll
    for (int i = 0; i < 8; ++i) {
      const int c = i * 256 + tid;
      const int row = c >> 4, s8 = (c & 15) * 8;
      const int slot = row0 + row;
      if (slot < row_end)
        *(u16x8*)(OUT + (long)slot * ldOut + n0 + s8) = *(const u16x8*)&lds[row * 128 + s8];
    }
  } else if constexpr (V == 3) {  // silu(conv) * up -> OUT (bf16, pure write)
#pragma unroll
    for (int mt = 0; mt < 2; ++mt)
#pragma unroll
      for (int r = 0; r < 4; ++r) {
        const int row = rbase + mt * 16 + quad * 4 + r;
#pragma unroll
        for (int nt = 0; nt < 8; ++nt) {
          float g = acc[mt][nt][r], u = acc2[mt][nt][r];
          lds[row * 128 + nt * 16 + l16] = f2bf(g / (1.f + __expf(-g)) * u);
        }
      }
    __syncthreads();
#pragma unroll
    for (int i = 0; i < 8; ++i) {
      const int c = i * 256 + tid;
      const int row = c >> 4, s8 = (c & 15) * 8;
      *(u16x8*)(OUT + (long)(row0 + row) * ldOut + n0 + s8) = *(const u16x8*)&lds[row * 128 + s8];
    }
  } else {  // V == 4: fp32 store + fused final combine
    // params repurposed: Bt1 = Y (bf16), tbl = slot_map, tok_w = topk_w,
    // tok_ids = (const int*)x (fp32 input)
    const u16* Yb = Bt1;
    const float* xf = (const float*)tok_ids;
#pragma unroll
    for (int mt = 0; mt < 2; ++mt)
#pragma unroll
      for (int r = 0; r < 4; ++r) {
        const int row = row0 + rbase + mt * 16 + quad * 4 + r;
        const int sm0 = tbl[row * 2], sm1 = tbl[row * 2 + 1];
        const float w0 = tok_w[row * 2], w1 = tok_w[row * 2 + 1];
#pragma unroll
        for (int nt = 0; nt < 8; ++nt) {
          const int col = n0 + nt * 16 + l16;
          float o = acc[mt][nt][r];
          if (sm0 >= 0) o += bf2f(Yb[(long)sm0 * 1024 + col]);
          else          o += w0 * xf[(long)row * 1024 + col];
          if (sm1 >= 0) o += bf2f(Yb[(long)sm1 * 1024 + col]);
          else          o += w1 * xf[(long)row * 1024 + col];
          OUTF[(long)row * ldOut + col] = o;
        }
      }
  }
}

extern "C" void kernel_launch(void* const* d_in, const int* in_sizes, int n_in,
                              void* d_out, int out_size, void* d_ws, size_t ws_size,
                              hipStream_t stream) {
  (void)in_sizes; (void)n_in; (void)out_size; (void)ws_size;
  const float* x   = (const float*)d_in[0];
  const float* rw  = (const float*)d_in[1];
  const float* rb  = (const float*)d_in[2];
  const float* gw  = (const float*)d_in[3];
  const float* uw  = (const float*)d_in[4];
  const float* dw  = (const float*)d_in[5];
  const float* cw  = (const float*)d_in[6];
  const float* suw = (const float*)d_in[7];
  const float* sdw = (const float*)d_in[8];
  float* out = (float*)d_out;

  char* base = (char*)d_ws;
  size_t off = 0;
  auto alloc = [&](size_t b) { void* p = base + off; off = (off + b + 255) & ~(size_t)255; return p; };
  u16* xb     = (u16*)alloc(16777216ull * 2);
  u16* gate_t = (u16*)alloc(15ull * 512 * 1024 * 2);
  u16* up_t   = (u16*)alloc(15ull * 512 * 1024 * 2);
  u16* down_t = (u16*)alloc(15ull * 1024 * 512 * 2);
  u16* conv_t = (u16*)alloc(3ull * 512 * 1024 * 2);
  u16* sup_t  = (u16*)alloc(512ull * 1024 * 2);
  u16* sdn_t  = (u16*)alloc(512ull * 1024 * 2);
  u16* inter  = (u16*)alloc(32768ull * 512 * 2);
  u16* Y      = (u16*)alloc(32768ull * 1024 * 2);
  u16* UP     = (u16*)alloc(16384ull * 512 * 2);
  int*   topi    = (int*)alloc(32768 * 4);
  float* topw    = (float*)alloc(32768 * 4);
  int*   smap    = (int*)alloc(32768 * 4);
  int*   tok_ids = (int*)alloc(32768 * 4);
  float* tokw    = (float*)alloc(32768 * 4);
  int*   ib      = (int*)alloc(8192);

  zero_k<<<1, 64, 0, stream>>>(ib);
  transpose_k<<<dim3(16, 32, 15), 256, 0, stream>>>(gw, gate_t, 1024, 512);
  transpose_k<<<dim3(16, 32, 15), 256, 0, stream>>>(uw, up_t, 1024, 512);
  transpose_k<<<dim3(32, 16, 15), 256, 0, stream>>>(dw, down_t, 512, 1024);
  transpose_k<<<dim3(16, 32, 1), 256, 0, stream>>>(suw, sup_t, 1024, 512);
  transpose_k<<<dim3(32, 16, 1), 256, 0, stream>>>(sdw, sdn_t, 512, 1024);
  convt_k<<<6144, 256, 0, stream>>>(cw, conv_t);
  router_k<<<256, 256, 0, stream>>>(x, rw, rb, topi, topw, ib, xb);  // + xb emit
  scan_k<<<1, 64, 0, stream>>>(ib);
  scatter_k<<<128, 256, 0, stream>>>(topi, topw, ib, tok_ids, tokw, smap);
  // routed experts (flat XCD-aware grids: 272*8, 272*8)
  gemm_k<0><<<2176, 256, 0, stream>>>(xb, gate_t, up_t, inter, ib + 64, ib + 48,
                                      tok_ids, tokw, 1024, 1024, 512);
  gemm_k<1><<<2176, 256, 0, stream>>>(inter, down_t, nullptr, Y, ib + 64, ib + 48,
                                      nullptr, tokw, 512, 512, 1024);
  // shared expert: fused conv-gate + up (flat: 128*4)
  gemm_k<3><<<512, 256, 0, stream>>>(xb, conv_t, sup_t, UP, nullptr, nullptr,
                                     nullptr, nullptr, 1024, 1024, 512);
  // shared-down + fused final combine (flat: 128*8)
  gemm_k<4><<<1024, 256, 0, stream>>>(UP, sdn_t, Y, out, smap, nullptr,
                                      (const int*)x, topw, 512, 512, 1024);
}

// Round 8
// 545.415 us; speedup vs baseline: 1.1065x; 1.1065x over previous
//
#include <hip/hip_runtime.h>

typedef unsigned short u16;
typedef __attribute__((ext_vector_type(4))) float f32x4;
using bf16x8 = __attribute__((ext_vector_type(8))) short;
typedef __attribute__((ext_vector_type(8))) unsigned short u16x8;
typedef __attribute__((ext_vector_type(4))) unsigned short u16x4;

#define GAS __attribute__((address_space(1)))
#define LAS __attribute__((address_space(3)))

__device__ __forceinline__ float bf2f(u16 u) {
  unsigned v = ((unsigned)u) << 16;
  float f;
  __builtin_memcpy(&f, &v, 4);
  return f;
}
__device__ __forceinline__ u16 f2bf(float f) {
  unsigned u;
  __builtin_memcpy(&u, &f, 4);
  u += 0x7fffu + ((u >> 16) & 1u);
  return (u16)(u >> 16);
}
__device__ __forceinline__ void llds16(const void* g, void* l) {
  __builtin_amdgcn_global_load_lds((const GAS unsigned*)g, (LAS unsigned*)l, 16, 0, 0);
}

// ---------------- router (+ fused x->xb bf16 conversion) ----------------
__global__ __launch_bounds__(256) void router_k(const float* __restrict__ x,
    const float* __restrict__ rw, const float* __restrict__ rb,
    int* __restrict__ topk_idx, float* __restrict__ topk_w, int* __restrict__ ib,
    u16* __restrict__ xb) {
  __shared__ float xs[4][32 * 65];    // [wave][h*65 + tok]
  __shared__ float wsm[4][32 * 16];   // [wave][h*16 + e]
  __shared__ float part[4][64 * 17];  // [wave][tok*17 + e]
  __shared__ int cnt[16];
  const int tid = threadIdx.x;
  const int wv = __builtin_amdgcn_readfirstlane(tid >> 6);
  const int lane = tid & 63;
  const int tok0 = blockIdx.x * 64;
  const int rr = lane >> 3;       // row-sub 0..7
  const int c4 = (lane & 7) * 4;  // col within 32-h chunk

  float acc[16];
#pragma unroll
  for (int e = 0; e < 16; ++e) acc[e] = 0.f;

  for (int c = 0; c < 8; ++c) {
    const int hb = wv * 256 + c * 32;
    // stage w chunk (512 contiguous floats)
    {
      f32x4 wa = *(const f32x4*)(rw + hb * 16 + lane * 4);
      f32x4 wb = *(const f32x4*)(rw + hb * 16 + 256 + lane * 4);
      *(f32x4*)&wsm[wv][lane * 4] = wa;
      *(f32x4*)&wsm[wv][256 + lane * 4] = wb;
    }
    // stage x chunk transposed + emit bf16 copy
#pragma unroll
    for (int i = 0; i < 8; ++i) {
      const int row = i * 8 + rr;
      const long gb = (long)(tok0 + row) * 1024 + hb + c4;
      f32x4 v = *(const f32x4*)(x + gb);
      u16x4 b4;
#pragma unroll
      for (int j = 0; j < 4; ++j) {
        xs[wv][(c4 + j) * 65 + row] = v[j];
        b4[j] = f2bf(v[j]);
      }
      *(u16x4*)(xb + gb) = b4;
    }
    __syncthreads();
#pragma unroll
    for (int h = 0; h < 32; ++h) {
      const float xv = xs[wv][h * 65 + lane];
      const float* wrow = &wsm[wv][h * 16];
#pragma unroll
      for (int q = 0; q < 4; ++q) {
        f32x4 w4 = *(const f32x4*)(wrow + q * 4);
#pragma unroll
        for (int e = 0; e < 4; ++e) acc[q * 4 + e] += xv * w4[e];
      }
    }
    __syncthreads();
  }
#pragma unroll
  for (int e = 0; e < 16; ++e) part[wv][lane * 17 + e] = acc[e];
  if (tid < 16) cnt[tid] = 0;
  __syncthreads();
  if (tid < 64) {
    float p[16];
#pragma unroll
    for (int e = 0; e < 16; ++e)
      p[e] = part[0][tid * 17 + e] + part[1][tid * 17 + e] +
             part[2][tid * 17 + e] + part[3][tid * 17 + e] + rb[e];
    float mx = p[0];
#pragma unroll
    for (int e = 1; e < 16; ++e) mx = fmaxf(mx, p[e]);
    float sum = 0.f;
#pragma unroll
    for (int e = 0; e < 16; ++e) { p[e] = __expf(p[e] - mx); sum += p[e]; }
    int i0 = 0; float p0 = p[0];
    for (int e = 1; e < 16; ++e) if (p[e] > p0) { p0 = p[e]; i0 = e; }
    int i1 = -1; float p1 = -1.f;
    for (int e = 0; e < 16; ++e) if (e != i0 && p[e] > p1) { p1 = p[e]; i1 = e; }
    const float inv = 1.f / sum;
    p0 *= inv; p1 *= inv;
    const float d = p0 + p1 + 1e-6f;
    const int t = tok0 + tid;
    topk_idx[t * 2] = i0; topk_idx[t * 2 + 1] = i1;
    topk_w[t * 2] = p0 / d;
    topk_w[t * 2 + 1] = p1 / d;
    if (i0 < 15) atomicAdd(&cnt[i0], 1);
    if (i1 < 15) atomicAdd(&cnt[i1], 1);
  }
  __syncthreads();
  if (tid < 15 && cnt[tid] > 0) atomicAdd(&ib[tid], cnt[tid]);
}

// ib layout: [0..15] counts, [16..31] offsets (offs[15]=total), [32..47] cursors,
//            [48] n_mtiles, [64..] mtile table {expert,row0,row_end,pad}
__global__ void zero_k(int* __restrict__ ib) {
  if (threadIdx.x < 16) ib[threadIdx.x] = 0;
}

__global__ void scan_k(int* __restrict__ ib) {
  if (threadIdx.x != 0 || blockIdx.x != 0) return;
  int off = 0;
  for (int ee = 0; ee < 15; ++ee) { ib[16 + ee] = off; ib[32 + ee] = off; off += ib[ee]; }
  ib[16 + 15] = off;
  int nm = 0;
  for (int ee = 0; ee < 15; ++ee) {
    const int st = ib[16 + ee], en = ib[16 + ee + 1];
    for (int r = st; r < en; r += 128) {
      ib[64 + nm * 4] = ee; ib[64 + nm * 4 + 1] = r; ib[64 + nm * 4 + 2] = en; ++nm;
    }
  }
  ib[48] = nm;
}

// scatter v2: per-block LDS aggregation, 15 global atomics/block
__global__ __launch_bounds__(256) void scatter_k(const int* __restrict__ topk_idx,
                          const float* __restrict__ topk_w,
                          int* __restrict__ ib, int* __restrict__ tok_ids,
                          float* __restrict__ tok_w, int* __restrict__ slot_map) {
  __shared__ int cnt[16], base[16];
  const int tid = threadIdx.x;
  const int j = blockIdx.x * 256 + tid;
  if (tid < 16) cnt[tid] = 0;
  __syncthreads();
  const int e = topk_idx[j];
  int lo = 0;
  if (e < 15) lo = atomicAdd(&cnt[e], 1);
  __syncthreads();
  if (tid < 15 && cnt[tid] > 0) base[tid] = atomicAdd(&ib[32 + tid], cnt[tid]);
  __syncthreads();
  if (e < 15) {
    const int pos = base[e] + lo;
    tok_ids[pos] = j >> 1;
    tok_w[pos] = topk_w[j];
    slot_map[j] = pos;
  } else {
    slot_map[j] = -1;
  }
}

// ------- weight transpose + fp32->bf16: dst[b][c][r] = src[b][r][c] -------
__global__ void transpose_k(const float* __restrict__ src, u16* __restrict__ dst, int R, int C) {
  __shared__ float tile[32][33];
  src += (long)blockIdx.z * R * C;
  dst += (long)blockIdx.z * R * C;
  const int c0 = blockIdx.x * 32, r0 = blockIdx.y * 32;
  const int tx = threadIdx.x & 31, ty = threadIdx.x >> 5;
#pragma unroll
  for (int i = ty; i < 32; i += 8) tile[i][tx] = src[(long)(r0 + i) * C + c0 + tx];
  __syncthreads();
#pragma unroll
  for (int i = ty; i < 32; i += 8) dst[(long)(c0 + i) * R + r0 + tx] = f2bf(tile[tx][i]);
}

// conv_w (I,H,KS) fp32 -> (KS, I, H) bf16
__global__ void convt_k(const float* __restrict__ cw, u16* __restrict__ dst) {
  const int idx = blockIdx.x * 256 + threadIdx.x;
  if (idx >= 3 * 512 * 1024) return;
  const int k = idx >> 19;
  const int rem = idx & 524287;
  const int i = rem >> 10, h = rem & 1023;
  dst[idx] = f2bf(cw[i * 3072 + h * 3 + k]);
}

// ---------------- unified MFMA GEMM, BM=128 ----------------
// Flat grid + XCD-aware remap (T1, round 3: FETCH 381->61MB, verified).
// V!=3 K-loop: 3-buffer depth-2 counted-vmcnt pipeline (round 6, verified).
// LDS chunk swizzle (rule #21): linear gload_lds dest + inverse-swizzled
// GLOBAL source + swizzled read: chunk' = chunk ^ ((row>>1)&3).
// V=0: gathered gate+up, fused silu*up -> inter (128 x 64 out, bf16)
// V=1: expert down (A=inter), fused *tok_w -> Y (128 x 128, bf16)
// V=3: FUSED shared expert up-path: 3 conv K-phases -> acc, + 1 phase
//      (B=Bt1=sup_t) -> acc2; epilogue writes f2bf(silu(conv)*up) to OUT.
// V=4: C = A @ B^T + FUSED final combine (LDS-staged, final_k-grade
//      coalescing: 32 lanes sweep one row's cols; slot_map wave-uniform).
template<int V>
__global__ __launch_bounds__(256, 2)
void gemm_k(const u16* __restrict__ Abase, const u16* __restrict__ Bt0,
            const u16* __restrict__ Bt1, void* __restrict__ OUTv,
            const int* __restrict__ tbl, const int* __restrict__ nmt,
            const int* __restrict__ tok_ids, const float* __restrict__ tok_w,
            int K, int ldA, int ldOut) {
  __shared__ u16 lds[24576];  // 48 KB: 3 staging buffers of 16 KB (V==3 uses 2)
  u16* OUT = (u16*)OUTv;
  float* OUTF = (float*)OUTv;
  const int tid = threadIdx.x;
  const int wave = tid >> 6, lane = tid & 63;
  const int quad = lane >> 4, l16 = lane & 15;
  const int rA = tid >> 2;           // staging row (and +64)
  const int sub8 = (tid & 3) * 8;    // linear dest chunk (V3 ds_write dest)
  const int sub8s = ((tid & 3) ^ ((tid >> 3) & 3)) * 8;  // swizzled source chunk

  // ---- XCD-aware flat-grid remap (grid size is always a multiple of 8) ----
  constexpr int NYC = (V == 3) ? 4 : 8;  // col-blocks per row-tile
  const int lin = (blockIdx.x & 7) * (gridDim.x >> 3) + (blockIdx.x >> 3);
  const int bx = lin / NYC, by = lin - bx * NYC;

  int e = 0, row0, row_end;
  if constexpr (V <= 1) {
    if (bx >= *nmt) return;
    e = tbl[bx * 4]; row0 = tbl[bx * 4 + 1]; row_end = tbl[bx * 4 + 2];
  } else {
    row0 = bx * 128; row_end = row0 + 128;
  }
  const int n0 = by * ((V == 0) ? 64 : 128);

  f32x4 acc[2][8];
  f32x4 acc2[2][8];  // only live for V==3 (DCE'd otherwise)
#pragma unroll
  for (int i = 0; i < 2; ++i)
#pragma unroll
    for (int j = 0; j < 8; ++j) {
      acc[i][j] = (f32x4){0.f, 0.f, 0.f, 0.f};
      if constexpr (V == 3) acc2[i][j] = (f32x4){0.f, 0.f, 0.f, 0.f};
    }

  // swizzled read chunk: for every A/B row this thread reads, (row>>1)&3 == (l16>>1)&3
  const int swz8 = (((l16 >> 1) & 3) ^ quad) * 8;
  const int aoff0 = (wave * 32 + l16) * 32 + swz8;
  const int aoff1 = aoff0 + 512;
  const int kIters = K / 32;

  if constexpr (V != 3) {
    const u16 *pA0, *pA1, *pB0, *pB1;
    if constexpr (V == 0) {
      const int t0i = tok_ids[min(row0 + rA, row_end - 1)];
      const int t1i = tok_ids[min(row0 + rA + 64, row_end - 1)];
      pA0 = Abase + (long)t0i * 1024 + sub8s;
      pA1 = Abase + (long)t1i * 1024 + sub8s;
      pB0 = Bt0 + ((long)e * 512 + n0 + rA) * 1024 + sub8s;  // gate
      pB1 = Bt1 + ((long)e * 512 + n0 + rA) * 1024 + sub8s;  // up
    } else if constexpr (V == 1) {
      pA0 = Abase + (long)min(row0 + rA, row_end - 1) * 512 + sub8s;
      pA1 = Abase + (long)min(row0 + rA + 64, row_end - 1) * 512 + sub8s;
      pB0 = Bt0 + ((long)e * 1024 + n0 + rA) * 512 + sub8s;
      pB1 = Bt0 + ((long)e * 1024 + n0 + rA + 64) * 512 + sub8s;
    } else {  // V == 4
      pA0 = Abase + (long)(row0 + rA) * ldA + sub8s;
      pA1 = Abase + (long)(row0 + rA + 64) * ldA + sub8s;
      pB0 = Bt0 + (long)(n0 + rA) * K + sub8s;
      pB1 = Bt0 + (long)(n0 + rA + 64) * K + sub8s;
    }
    auto STAGE = [&](int buf) {
      llds16(pA0, &lds[buf + wave * 512]); pA0 += 32;
      llds16(pA1, &lds[buf + 2048 + wave * 512]); pA1 += 32;
      llds16(pB0, &lds[buf + 4096 + wave * 512]); pB0 += 32;
      llds16(pB1, &lds[buf + 6144 + wave * 512]); pB1 += 32;
    };
    // prologue: tiles 0 and 1 in flight
    STAGE(0);
    STAGE(8192);
    int cur = 0, stg = 16384;
    for (int kb = 0; kb < kIters; ++kb) {
      if (kb + 1 < kIters) {
        asm volatile("s_waitcnt vmcnt(4)" ::: "memory");  // tile kb landed
      } else {
        asm volatile("s_waitcnt vmcnt(0)" ::: "memory");  // tail: drain last tile
      }
      __builtin_amdgcn_s_barrier();  // raw: tile kb+1 DMA stays in flight
      if (kb + 2 < kIters) {
        STAGE(stg);  // buffer last read 2 iters ago: reader-free
        stg = (stg == 16384) ? 0 : stg + 8192;
      }
      bf16x8 a0 = *(const bf16x8*)&lds[cur + aoff0];
      bf16x8 a1 = *(const bf16x8*)&lds[cur + aoff1];
      __builtin_amdgcn_s_setprio(1);
#pragma unroll
      for (int nt = 0; nt < 8; ++nt) {
        bf16x8 b = *(const bf16x8*)&lds[cur + 4096 + (nt * 16 + l16) * 32 + swz8];
        acc[0][nt] = __builtin_amdgcn_mfma_f32_16x16x32_bf16(a0, b, acc[0][nt], 0, 0, 0);
        acc[1][nt] = __builtin_amdgcn_mfma_f32_16x16x32_bf16(a1, b, acc[1][nt], 0, 0, 0);
      }
      __builtin_amdgcn_s_setprio(0);
      cur = (cur == 16384) ? 0 : cur + 8192;
    }
    __builtin_amdgcn_s_barrier();  // all waves done with last tile: LDS reusable
  } else {
    // ---- V == 3 fused: conv phases 0..2 -> acc; sup phase -> acc2 ----
    int cur = 0;
    u16x8 va0n, va1n;
    const int bb = row0 >> 12, s0 = row0 & 4095;
    for (int ph = 0; ph < 3; ++ph) {
      const u16 *pA0, *pA1, *pB0, *pB1;
      const int si0 = s0 + ph - 2 + rA;
      const bool zero0 = si0 < 0;
      pA0 = Abase + ((long)bb * 4096 + (si0 < 0 ? 0 : si0)) * 1024 + sub8s;
      pA1 = Abase + ((long)bb * 4096 + (si0 + 64)) * 1024 + sub8s;
      pB0 = Bt0 + (long)ph * 524288 + (long)(n0 + rA) * 1024 + sub8s;
      pB1 = Bt0 + (long)ph * 524288 + (long)(n0 + rA + 64) * 1024 + sub8s;

      va0n = *(const u16x8*)pA0; pA0 += 32;
      va1n = *(const u16x8*)pA1; pA1 += 32;
      if (zero0) va0n = (u16x8){0, 0, 0, 0, 0, 0, 0, 0};
      *(u16x8*)&lds[cur + rA * 32 + sub8] = va0n;
      *(u16x8*)&lds[cur + (rA + 64) * 32 + sub8] = va1n;
      llds16(pB0, &lds[cur + 4096 + wave * 512]); pB0 += 32;
      llds16(pB1, &lds[cur + 6144 + wave * 512]); pB1 += 32;
      __syncthreads();  // k=0 resident

      for (int kb = 0; kb < kIters; ++kb) {
        const int nxt = cur ^ 8192;
        const bool pre = (kb + 1 < kIters);
        if (pre) {
          llds16(pB0, &lds[nxt + 4096 + wave * 512]); pB0 += 32;
          llds16(pB1, &lds[nxt + 6144 + wave * 512]); pB1 += 32;
          va0n = *(const u16x8*)pA0; pA0 += 32;
          va1n = *(const u16x8*)pA1; pA1 += 32;
          if (zero0) va0n = (u16x8){0, 0, 0, 0, 0, 0, 0, 0};
        }
        bf16x8 a0 = *(const bf16x8*)&lds[cur + aoff0];
        bf16x8 a1 = *(const bf16x8*)&lds[cur + aoff1];
#pragma unroll
        for (int nt = 0; nt < 8; ++nt) {
          bf16x8 b = *(const bf16x8*)&lds[cur + 4096 + (nt * 16 + l16) * 32 + swz8];
          acc[0][nt] = __builtin_amdgcn_mfma_f32_16x16x32_bf16(a0, b, acc[0][nt], 0, 0, 0);
          acc[1][nt] = __builtin_amdgcn_mfma_f32_16x16x32_bf16(a1, b, acc[1][nt], 0, 0, 0);
        }
        if (pre) {
          *(u16x8*)&lds[nxt + rA * 32 + sub8] = va0n;
          *(u16x8*)&lds[nxt + (rA + 64) * 32 + sub8] = va1n;
        }
        __syncthreads();
        cur = nxt;
      }
    }
    // ---- phase 3: B = sup_t (Bt1), A unshifted; accumulate into acc2 ----
    {
      const u16* pA0 = Abase + ((long)bb * 4096 + s0 + rA) * 1024 + sub8s;
      const u16* pA1 = Abase + ((long)bb * 4096 + s0 + rA + 64) * 1024 + sub8s;
      const u16* pB0 = Bt1 + (long)(n0 + rA) * 1024 + sub8s;
      const u16* pB1 = Bt1 + (long)(n0 + rA + 64) * 1024 + sub8s;

      va0n = *(const u16x8*)pA0; pA0 += 32;
      va1n = *(const u16x8*)pA1; pA1 += 32;
      *(u16x8*)&lds[cur + rA * 32 + sub8] = va0n;
      *(u16x8*)&lds[cur + (rA + 64) * 32 + sub8] = va1n;
      llds16(pB0, &lds[cur + 4096 + wave * 512]); pB0 += 32;
      llds16(pB1, &lds[cur + 6144 + wave * 512]); pB1 += 32;
      __syncthreads();

      for (int kb = 0; kb < kIters; ++kb) {
        const int nxt = cur ^ 8192;
        const bool pre = (kb + 1 < kIters);
        if (pre) {
          llds16(pB0, &lds[nxt + 4096 + wave * 512]); pB0 += 32;
          llds16(pB1, &lds[nxt + 6144 + wave * 512]); pB1 += 32;
          va0n = *(const u16x8*)pA0; pA0 += 32;
          va1n = *(const u16x8*)pA1; pA1 += 32;
        }
        bf16x8 a0 = *(const bf16x8*)&lds[cur + aoff0];
        bf16x8 a1 = *(const bf16x8*)&lds[cur + aoff1];
#pragma unroll
        for (int nt = 0; nt < 8; ++nt) {
          bf16x8 b = *(const bf16x8*)&lds[cur + 4096 + (nt * 16 + l16) * 32 + swz8];
          acc2[0][nt] = __builtin_amdgcn_mfma_f32_16x16x32_bf16(a0, b, acc2[0][nt], 0, 0, 0);
          acc2[1][nt] = __builtin_amdgcn_mfma_f32_16x16x32_bf16(a1, b, acc2[1][nt], 0, 0, 0);
        }
        if (pre) {
          *(u16x8*)&lds[nxt + rA * 32 + sub8] = va0n;
          *(u16x8*)&lds[nxt + (rA + 64) * 32 + sub8] = va1n;
        }
        __syncthreads();
        cur = nxt;
      }
    }
  }

  // ---- epilogue ----
  const int rbase = wave * 32;
  if constexpr (V == 0) {
#pragma unroll
    for (int mt = 0; mt < 2; ++mt)
#pragma unroll
      for (int r = 0; r < 4; ++r) {
        const int row = rbase + mt * 16 + quad * 4 + r;
#pragma unroll
        for (int nt = 0; nt < 4; ++nt) {
          float g = acc[mt][nt][r], u = acc[mt][nt + 4][r];
          float sg = g / (1.f + __expf(-g));
          lds[row * 64 + nt * 16 + l16] = f2bf(sg * u);
        }
      }
    __syncthreads();
#pragma unroll
    for (int i = 0; i < 4; ++i) {
      const int c = i * 256 + tid;
      const int row = c >> 3, s8 = (c & 7) * 8;
      const int slot = row0 + row;
      if (slot < row_end)
        *(u16x8*)(OUT + (long)slot * ldOut + n0 + s8) = *(const u16x8*)&lds[row * 64 + s8];
    }
  } else if constexpr (V == 1) {
#pragma unroll
    for (int mt = 0; mt < 2; ++mt)
#pragma unroll
      for (int r = 0; r < 4; ++r) {
        const int row = rbase + mt * 16 + quad * 4 + r;
        const float wgt = tok_w[min(row0 + row, row_end - 1)];
#pragma unroll
        for (int nt = 0; nt < 8; ++nt)
          lds[row * 128 + nt * 16 + l16] = f2bf(acc[mt][nt][r] * wgt);
      }
    __syncthreads();
#pragma unroll
    for (int i = 0; i < 8; ++i) {
      const int c = i * 256 + tid;
      const int row = c >> 4, s8 = (c & 15) * 8;
      const int slot = row0 + row;
      if (slot < row_end)
        *(u16x8*)(OUT + (long)slot * ldOut + n0 + s8) = *(const u16x8*)&lds[row * 128 + s8];
    }
  } else if constexpr (V == 3) {  // silu(conv) * up -> OUT (bf16, pure write)
#pragma unroll
    for (int mt = 0; mt < 2; ++mt)
#pragma unroll
      for (int r = 0; r < 4; ++r) {
        const int row = rbase + mt * 16 + quad * 4 + r;
#pragma unroll
        for (int nt = 0; nt < 8; ++nt) {
          float g = acc[mt][nt][r], u = acc2[mt][nt][r];
          lds[row * 128 + nt * 16 + l16] = f2bf(g / (1.f + __expf(-g)) * u);
        }
      }
    __syncthreads();
#pragma unroll
    for (int i = 0; i < 8; ++i) {
      const int c = i * 256 + tid;
      const int row = c >> 4, s8 = (c & 15) * 8;
      *(u16x8*)(OUT + (long)(row0 + row) * ldOut + n0 + s8) = *(const u16x8*)&lds[row * 128 + s8];
    }
  } else {  // V == 4: fused final combine, LDS-staged for coalescing
    // params repurposed: Bt1 = Y (bf16), tbl = slot_map, tok_w = topk_w,
    // tok_ids = (const int*)x (fp32 input)
    const u16* Yb = Bt1;
    const float* xf = (const float*)tok_ids;
    float* ldsF = (float*)lds;  // 64 rows x 128 cols fp32 = 32 KB
#pragma unroll
    for (int p = 0; p < 2; ++p) {
      if (p) __syncthreads();  // pass-0 reads done before overwrite
      if ((wave >> 1) == p) {
        const int lw = wave & 1;
#pragma unroll
        for (int mt = 0; mt < 2; ++mt)
#pragma unroll
          for (int r = 0; r < 4; ++r) {
            const int lrow = lw * 32 + mt * 16 + quad * 4 + r;
#pragma unroll
            for (int nt = 0; nt < 8; ++nt)
              ldsF[lrow * 128 + nt * 16 + l16] = acc[mt][nt][r];
          }
      }
      __syncthreads();
      // combine: 32 consecutive lanes sweep one row (f32x4 chunks) -> coalesced
#pragma unroll
      for (int i = 0; i < 8; ++i) {
        const int c = i * 256 + tid;
        const int lrow = c >> 5, c4 = (c & 31) * 4;
        const int grow = row0 + p * 64 + lrow;
        f32x4 o = *(const f32x4*)&ldsF[lrow * 128 + c4];
        const int sm0 = tbl[grow * 2], sm1 = tbl[grow * 2 + 1];
#pragma unroll
        for (int k2 = 0; k2 < 2; ++k2) {
          const int sm = k2 ? sm1 : sm0;
          if (sm >= 0) {
            u16x4 y = *(const u16x4*)(Yb + (long)sm * 1024 + n0 + c4);
#pragma unroll
            for (int j = 0; j < 4; ++j) o[j] += bf2f(y[j]);
          } else {
            const float w = tok_w[grow * 2 + k2];
            f32x4 xv = *(const f32x4*)(xf + (long)grow * 1024 + n0 + c4);
#pragma unroll
            for (int j = 0; j < 4; ++j) o[j] += w * xv[j];
          }
        }
        *(f32x4*)(OUTF + (long)grow * ldOut + n0 + c4) = o;
      }
    }
  }
}

extern "C" void kernel_launch(void* const* d_in, const int* in_sizes, int n_in,
                              void* d_out, int out_size, void* d_ws, size_t ws_size,
                              hipStream_t stream) {
  (void)in_sizes; (void)n_in; (void)out_size; (void)ws_size;
  const float* x   = (const float*)d_in[0];
  const float* rw  = (const float*)d_in[1];
  const float* rb  = (const float*)d_in[2];
  const float* gw  = (const float*)d_in[3];
  const float* uw  = (const float*)d_in[4];
  const float* dw  = (const float*)d_in[5];
  const float* cw  = (const float*)d_in[6];
  const float* suw = (const float*)d_in[7];
  const float* sdw = (const float*)d_in[8];
  float* out = (float*)d_out;

  char* base = (char*)d_ws;
  size_t off = 0;
  auto alloc = [&](size_t b) { void* p = base + off; off = (off + b + 255) & ~(size_t)255; return p; };
  u16* xb     = (u16*)alloc(16777216ull * 2);
  u16* gate_t = (u16*)alloc(15ull * 512 * 1024 * 2);
  u16* up_t   = (u16*)alloc(15ull * 512 * 1024 * 2);
  u16* down_t = (u16*)alloc(15ull * 1024 * 512 * 2);
  u16* conv_t = (u16*)alloc(3ull * 512 * 1024 * 2);
  u16* sup_t  = (u16*)alloc(512ull * 1024 * 2);
  u16* sdn_t  = (u16*)alloc(512ull * 1024 * 2);
  u16* inter  = (u16*)alloc(32768ull * 512 * 2);
  u16* Y      = (u16*)alloc(32768ull * 1024 * 2);
  u16* UP     = (u16*)alloc(16384ull * 512 * 2);
  int*   topi    = (int*)alloc(32768 * 4);
  float* topw    = (float*)alloc(32768 * 4);
  int*   smap    = (int*)alloc(32768 * 4);
  int*   tok_ids = (int*)alloc(32768 * 4);
  float* tokw    = (float*)alloc(32768 * 4);
  int*   ib      = (int*)alloc(8192);

  zero_k<<<1, 64, 0, stream>>>(ib);
  transpose_k<<<dim3(16, 32, 15), 256, 0, stream>>>(gw, gate_t, 1024, 512);
  transpose_k<<<dim3(16, 32, 15), 256, 0, stream>>>(uw, up_t, 1024, 512);
  transpose_k<<<dim3(32, 16, 15), 256, 0, stream>>>(dw, down_t, 512, 1024);
  transpose_k<<<dim3(16, 32, 1), 256, 0, stream>>>(suw, sup_t, 1024, 512);
  transpose_k<<<dim3(32, 16, 1), 256, 0, stream>>>(sdw, sdn_t, 512, 1024);
  convt_k<<<6144, 256, 0, stream>>>(cw, conv_t);
  router_k<<<256, 256, 0, stream>>>(x, rw, rb, topi, topw, ib, xb);  // + xb emit
  scan_k<<<1, 64, 0, stream>>>(ib);
  scatter_k<<<128, 256, 0, stream>>>(topi, topw, ib, tok_ids, tokw, smap);
  // routed experts (flat XCD-aware grids: 272*8, 272*8)
  gemm_k<0><<<2176, 256, 0, stream>>>(xb, gate_t, up_t, inter, ib + 64, ib + 48,
                                      tok_ids, tokw, 1024, 1024, 512);
  gemm_k<1><<<2176, 256, 0, stream>>>(inter, down_t, nullptr, Y, ib + 64, ib + 48,
                                      nullptr, tokw, 512, 512, 1024);
  // shared expert: fused conv-gate + up (flat: 128*4)
  gemm_k<3><<<512, 256, 0, stream>>>(xb, conv_t, sup_t, UP, nullptr, nullptr,
                                     nullptr, nullptr, 1024, 1024, 512);
  // shared-down + fused final combine (flat: 128*8)
  gemm_k<4><<<1024, 256, 0, stream>>>(UP, sdn_t, Y, out, smap, nullptr,
                                      (const int*)x, topw, 512, 512, 1024);
}

// Round 9
// 544.337 us; speedup vs baseline: 1.1087x; 1.0020x over previous
//
#include <hip/hip_runtime.h>

typedef unsigned short u16;
typedef __attribute__((ext_vector_type(4))) float f32x4;
using bf16x8 = __attribute__((ext_vector_type(8))) short;
typedef __attribute__((ext_vector_type(8))) unsigned short u16x8;
typedef __attribute__((ext_vector_type(4))) unsigned short u16x4;

#define GAS __attribute__((address_space(1)))
#define LAS __attribute__((address_space(3)))

__device__ __forceinline__ float bf2f(u16 u) {
  unsigned v = ((unsigned)u) << 16;
  float f;
  __builtin_memcpy(&f, &v, 4);
  return f;
}
__device__ __forceinline__ u16 f2bf(float f) {
  unsigned u;
  __builtin_memcpy(&u, &f, 4);
  u += 0x7fffu + ((u >> 16) & 1u);
  return (u16)(u >> 16);
}
__device__ __forceinline__ void llds16(const void* g, void* l) {
  __builtin_amdgcn_global_load_lds((const GAS unsigned*)g, (LAS unsigned*)l, 16, 0, 0);
}

// ---------------- router (+ fused x->xb bf16 conversion) ----------------
__global__ __launch_bounds__(256) void router_k(const float* __restrict__ x,
    const float* __restrict__ rw, const float* __restrict__ rb,
    int* __restrict__ topk_idx, float* __restrict__ topk_w, int* __restrict__ ib,
    u16* __restrict__ xb) {
  __shared__ float xs[4][32 * 65];    // [wave][h*65 + tok]
  __shared__ float wsm[4][32 * 16];   // [wave][h*16 + e]
  __shared__ float part[4][64 * 17];  // [wave][tok*17 + e]
  __shared__ int cnt[16];
  const int tid = threadIdx.x;
  const int wv = __builtin_amdgcn_readfirstlane(tid >> 6);
  const int lane = tid & 63;
  const int tok0 = blockIdx.x * 64;
  const int rr = lane >> 3;       // row-sub 0..7
  const int c4 = (lane & 7) * 4;  // col within 32-h chunk

  float acc[16];
#pragma unroll
  for (int e = 0; e < 16; ++e) acc[e] = 0.f;

  for (int c = 0; c < 8; ++c) {
    const int hb = wv * 256 + c * 32;
    // stage w chunk (512 contiguous floats)
    {
      f32x4 wa = *(const f32x4*)(rw + hb * 16 + lane * 4);
      f32x4 wb = *(const f32x4*)(rw + hb * 16 + 256 + lane * 4);
      *(f32x4*)&wsm[wv][lane * 4] = wa;
      *(f32x4*)&wsm[wv][256 + lane * 4] = wb;
    }
    // stage x chunk transposed + emit bf16 copy
#pragma unroll
    for (int i = 0; i < 8; ++i) {
      const int row = i * 8 + rr;
      const long gb = (long)(tok0 + row) * 1024 + hb + c4;
      f32x4 v = *(const f32x4*)(x + gb);
      u16x4 b4;
#pragma unroll
      for (int j = 0; j < 4; ++j) {
        xs[wv][(c4 + j) * 65 + row] = v[j];
        b4[j] = f2bf(v[j]);
      }
      *(u16x4*)(xb + gb) = b4;
    }
    __syncthreads();
#pragma unroll
    for (int h = 0; h < 32; ++h) {
      const float xv = xs[wv][h * 65 + lane];
      const float* wrow = &wsm[wv][h * 16];
#pragma unroll
      for (int q = 0; q < 4; ++q) {
        f32x4 w4 = *(const f32x4*)(wrow + q * 4);
#pragma unroll
        for (int e = 0; e < 4; ++e) acc[q * 4 + e] += xv * w4[e];
      }
    }
    __syncthreads();
  }
#pragma unroll
  for (int e = 0; e < 16; ++e) part[wv][lane * 17 + e] = acc[e];
  if (tid < 16) cnt[tid] = 0;
  __syncthreads();
  if (tid < 64) {
    float p[16];
#pragma unroll
    for (int e = 0; e < 16; ++e)
      p[e] = part[0][tid * 17 + e] + part[1][tid * 17 + e] +
             part[2][tid * 17 + e] + part[3][tid * 17 + e] + rb[e];
    float mx = p[0];
#pragma unroll
    for (int e = 1; e < 16; ++e) mx = fmaxf(mx, p[e]);
    float sum = 0.f;
#pragma unroll
    for (int e = 0; e < 16; ++e) { p[e] = __expf(p[e] - mx); sum += p[e]; }
    int i0 = 0; float p0 = p[0];
    for (int e = 1; e < 16; ++e) if (p[e] > p0) { p0 = p[e]; i0 = e; }
    int i1 = -1; float p1 = -1.f;
    for (int e = 0; e < 16; ++e) if (e != i0 && p[e] > p1) { p1 = p[e]; i1 = e; }
    const float inv = 1.f / sum;
    p0 *= inv; p1 *= inv;
    const float d = p0 + p1 + 1e-6f;
    const int t = tok0 + tid;
    topk_idx[t * 2] = i0; topk_idx[t * 2 + 1] = i1;
    topk_w[t * 2] = p0 / d;
    topk_w[t * 2 + 1] = p1 / d;
    if (i0 < 15) atomicAdd(&cnt[i0], 1);
    if (i1 < 15) atomicAdd(&cnt[i1], 1);
  }
  __syncthreads();
  if (tid < 15 && cnt[tid] > 0) atomicAdd(&ib[tid], cnt[tid]);
}

// ib layout: [0..15] counts, [16..31] offsets (offs[15]=total), [32..47] cursors,
//            [48] n_mtiles, [64..] mtile table {expert,row0,row_end,pad}
__global__ void zero_k(int* __restrict__ ib) {
  if (threadIdx.x < 16) ib[threadIdx.x] = 0;
}

__global__ void scan_k(int* __restrict__ ib) {
  if (threadIdx.x != 0 || blockIdx.x != 0) return;
  int off = 0;
  for (int ee = 0; ee < 15; ++ee) { ib[16 + ee] = off; ib[32 + ee] = off; off += ib[ee]; }
  ib[16 + 15] = off;
  int nm = 0;
  for (int ee = 0; ee < 15; ++ee) {
    const int st = ib[16 + ee], en = ib[16 + ee + 1];
    for (int r = st; r < en; r += 128) {
      ib[64 + nm * 4] = ee; ib[64 + nm * 4 + 1] = r; ib[64 + nm * 4 + 2] = en; ++nm;
    }
  }
  ib[48] = nm;
}

// scatter v2: per-block LDS aggregation, 15 global atomics/block
__global__ __launch_bounds__(256) void scatter_k(const int* __restrict__ topk_idx,
                          const float* __restrict__ topk_w,
                          int* __restrict__ ib, int* __restrict__ tok_ids,
                          float* __restrict__ tok_w, int* __restrict__ slot_map) {
  __shared__ int cnt[16], base[16];
  const int tid = threadIdx.x;
  const int j = blockIdx.x * 256 + tid;
  if (tid < 16) cnt[tid] = 0;
  __syncthreads();
  const int e = topk_idx[j];
  int lo = 0;
  if (e < 15) lo = atomicAdd(&cnt[e], 1);
  __syncthreads();
  if (tid < 15 && cnt[tid] > 0) base[tid] = atomicAdd(&ib[32 + tid], cnt[tid]);
  __syncthreads();
  if (e < 15) {
    const int pos = base[e] + lo;
    tok_ids[pos] = j >> 1;
    tok_w[pos] = topk_w[j];
    slot_map[j] = pos;
  } else {
    slot_map[j] = -1;
  }
}

// ------- weight transpose + fp32->bf16: dst[b][c][r] = src[b][r][c] -------
__global__ void transpose_k(const float* __restrict__ src, u16* __restrict__ dst, int R, int C) {
  __shared__ float tile[32][33];
  src += (long)blockIdx.z * R * C;
  dst += (long)blockIdx.z * R * C;
  const int c0 = blockIdx.x * 32, r0 = blockIdx.y * 32;
  const int tx = threadIdx.x & 31, ty = threadIdx.x >> 5;
#pragma unroll
  for (int i = ty; i < 32; i += 8) tile[i][tx] = src[(long)(r0 + i) * C + c0 + tx];
  __syncthreads();
#pragma unroll
  for (int i = ty; i < 32; i += 8) dst[(long)(c0 + i) * R + r0 + tx] = f2bf(tile[tx][i]);
}

// conv_w (I,H,KS) fp32 -> (KS, I, H) bf16
__global__ void convt_k(const float* __restrict__ cw, u16* __restrict__ dst) {
  const int idx = blockIdx.x * 256 + threadIdx.x;
  if (idx >= 3 * 512 * 1024) return;
  const int k = idx >> 19;
  const int rem = idx & 524287;
  const int i = rem >> 10, h = rem & 1023;
  dst[idx] = f2bf(cw[i * 3072 + h * 3 + k]);
}

// ---------------- unified MFMA GEMM, BM=128 ----------------
// Flat grid + XCD-aware remap (T1, verified). V0/1/4 K-loop: 3-buffer depth-2
// counted-vmcnt pipeline (round 6, verified) + LDS chunk swizzle (rule #21).
// V=0: gathered gate+up, fused silu*up -> inter (128 x 64 out, bf16)
// V=1: expert down (A=inter), fused *tok_w -> Y (128 x 128, bf16)
// V=3: SINGLE-PASS fused shared-expert up-path: one 130-row A-window
//      (tokens s0-2..s0+127) staged per K-step; 4 B-mats (conv taps 0..2 +
//      sup) x 64 cols; tap ph reads lds row ro+ph (up == tap2 rows).
//      32 K-steps, 32 MFMA/wave/barrier-pair (was 128 steps x 16).
//      Out: f2bf(silu(conv)*up), 128 x 64 bf16.
// V=4: C = A @ B^T + FUSED final combine (LDS-staged coalesced sweep).
template<int V>
__global__ __launch_bounds__(256, 2)
void gemm_k(const u16* __restrict__ Abase, const u16* __restrict__ Bt0,
            const u16* __restrict__ Bt1, void* __restrict__ OUTv,
            const int* __restrict__ tbl, const int* __restrict__ nmt,
            const int* __restrict__ tok_ids, const float* __restrict__ tok_w,
            int K, int ldA, int ldOut) {
  __shared__ u16 lds[24832];  // V3: 2 x 12416; V0/1/4: 3 x 8192
  u16* OUT = (u16*)OUTv;
  float* OUTF = (float*)OUTv;
  const int tid = threadIdx.x;
  const int wave = tid >> 6, lane = tid & 63;
  const int quad = lane >> 4, l16 = lane & 15;
  const int rA = tid >> 2;           // staging row (and +64)
  const int sub8s = ((tid & 3) ^ ((tid >> 3) & 3)) * 8;  // swizzled source chunk

  // ---- XCD-aware flat-grid remap (grid size is always a multiple of 8) ----
  constexpr int NYC = 8;  // col-blocks per row-tile (all variants)
  const int lin = (blockIdx.x & 7) * (gridDim.x >> 3) + (blockIdx.x >> 3);
  const int bx = lin / NYC, by = lin - bx * NYC;

  int e = 0, row0, row_end;
  if constexpr (V <= 1) {
    if (bx >= *nmt) return;
    e = tbl[bx * 4]; row0 = tbl[bx * 4 + 1]; row_end = tbl[bx * 4 + 2];
  } else {
    row0 = bx * 128; row_end = row0 + 128;
  }
  const int n0 = by * ((V == 0 || V == 3) ? 64 : 128);

  f32x4 acc[2][8];
  f32x4 acc2[2][4];  // only live for V==3 (DCE'd otherwise)
#pragma unroll
  for (int i = 0; i < 2; ++i) {
#pragma unroll
    for (int j = 0; j < 8; ++j) acc[i][j] = (f32x4){0.f, 0.f, 0.f, 0.f};
    if constexpr (V == 3)
#pragma unroll
      for (int j = 0; j < 4; ++j) acc2[i][j] = (f32x4){0.f, 0.f, 0.f, 0.f};
  }

  // swizzled read chunk (V0/1/4): (row>>1)&3 == (l16>>1)&3 for all staged rows
  const int swz8 = (((l16 >> 1) & 3) ^ quad) * 8;
  const int aoff0 = (wave * 32 + l16) * 32 + swz8;
  const int aoff1 = aoff0 + 512;
  const int kIters = K / 32;

  if constexpr (V != 3) {
    const u16 *pA0, *pA1, *pB0, *pB1;
    if constexpr (V == 0) {
      const int t0i = tok_ids[min(row0 + rA, row_end - 1)];
      const int t1i = tok_ids[min(row0 + rA + 64, row_end - 1)];
      pA0 = Abase + (long)t0i * 1024 + sub8s;
      pA1 = Abase + (long)t1i * 1024 + sub8s;
      pB0 = Bt0 + ((long)e * 512 + n0 + rA) * 1024 + sub8s;  // gate
      pB1 = Bt1 + ((long)e * 512 + n0 + rA) * 1024 + sub8s;  // up
    } else if constexpr (V == 1) {
      pA0 = Abase + (long)min(row0 + rA, row_end - 1) * 512 + sub8s;
      pA1 = Abase + (long)min(row0 + rA + 64, row_end - 1) * 512 + sub8s;
      pB0 = Bt0 + ((long)e * 1024 + n0 + rA) * 512 + sub8s;
      pB1 = Bt0 + ((long)e * 1024 + n0 + rA + 64) * 512 + sub8s;
    } else {  // V == 4
      pA0 = Abase + (long)(row0 + rA) * ldA + sub8s;
      pA1 = Abase + (long)(row0 + rA + 64) * ldA + sub8s;
      pB0 = Bt0 + (long)(n0 + rA) * K + sub8s;
      pB1 = Bt0 + (long)(n0 + rA + 64) * K + sub8s;
    }
    auto STAGE = [&](int buf) {
      llds16(pA0, &lds[buf + wave * 512]); pA0 += 32;
      llds16(pA1, &lds[buf + 2048 + wave * 512]); pA1 += 32;
      llds16(pB0, &lds[buf + 4096 + wave * 512]); pB0 += 32;
      llds16(pB1, &lds[buf + 6144 + wave * 512]); pB1 += 32;
    };
    // prologue: tiles 0 and 1 in flight
    STAGE(0);
    STAGE(8192);
    int cur = 0, stg = 16384;
    for (int kb = 0; kb < kIters; ++kb) {
      if (kb + 1 < kIters) {
        asm volatile("s_waitcnt vmcnt(4)" ::: "memory");  // tile kb landed
      } else {
        asm volatile("s_waitcnt vmcnt(0)" ::: "memory");  // tail: drain last tile
      }
      __builtin_amdgcn_s_barrier();  // raw: tile kb+1 DMA stays in flight
      if (kb + 2 < kIters) {
        STAGE(stg);  // buffer last read 2 iters ago: reader-free
        stg = (stg == 16384) ? 0 : stg + 8192;
      }
      bf16x8 a0 = *(const bf16x8*)&lds[cur + aoff0];
      bf16x8 a1 = *(const bf16x8*)&lds[cur + aoff1];
      __builtin_amdgcn_s_setprio(1);
#pragma unroll
      for (int nt = 0; nt < 8; ++nt) {
        bf16x8 b = *(const bf16x8*)&lds[cur + 4096 + (nt * 16 + l16) * 32 + swz8];
        acc[0][nt] = __builtin_amdgcn_mfma_f32_16x16x32_bf16(a0, b, acc[0][nt], 0, 0, 0);
        acc[1][nt] = __builtin_amdgcn_mfma_f32_16x16x32_bf16(a1, b, acc[1][nt], 0, 0, 0);
      }
      __builtin_amdgcn_s_setprio(0);
      cur = (cur == 16384) ? 0 : cur + 8192;
    }
    __builtin_amdgcn_s_barrier();  // all waves done with last tile: LDS reusable
  } else {
    // ---- V == 3 single-pass: A-window 130 rows @0..4223, 4 B mats @4224 ----
    constexpr int BUF = 12416;
    const int bb = row0 >> 12, s0 = row0 & 4095;
    const int q8 = (tid & 3) * 8;
    const int rowA0 = tid >> 2;          // 0..63
    const int rowA1 = 64 + (tid >> 2);   // 64..127
    const int rowAx = 128 + (tid >> 2);  // 128..129 (tid<8 only)
    const long xbase = (long)bb * 4096;
    const int si0 = s0 - 2 + rowA0;
    const bool z0 = si0 < 0;  // causal clamp: only window rows 0,1 at s0==0
    const u16* pA0g = Abase + (xbase + (si0 < 0 ? 0 : si0)) * 1024 + q8;
    const u16* pA1g = Abase + (xbase + (long)(s0 - 2 + rowA1)) * 1024 + q8;
    const u16* pAxg = Abase + (xbase + (long)(s0 - 2 + rowAx)) * 1024 + q8;
    const u16* pB0g = Bt0 + (long)(n0 + (tid >> 2)) * 1024 + q8;            // tap0
    const u16* pB3g = Bt1 + (long)(n0 + (tid >> 2)) * 1024 + q8;            // sup
    u16x8 vA0, vA1, vAx;

    int cur = 0;
    // prologue: stage kb=0
    vA0 = *(const u16x8*)pA0g;
    vA1 = *(const u16x8*)pA1g;
    if (tid < 8) vAx = *(const u16x8*)pAxg;
    if (z0) vA0 = (u16x8){0, 0, 0, 0, 0, 0, 0, 0};
    *(u16x8*)&lds[cur + rowA0 * 32 + q8] = vA0;
    *(u16x8*)&lds[cur + rowA1 * 32 + q8] = vA1;
    if (tid < 8) *(u16x8*)&lds[cur + rowAx * 32 + q8] = vAx;
    llds16(pB0g, &lds[cur + 4224 + wave * 512]);
    llds16(pB0g + 524288, &lds[cur + 4224 + 2048 + wave * 512]);
    llds16(pB0g + 1048576, &lds[cur + 4224 + 4096 + wave * 512]);
    llds16(pB3g, &lds[cur + 4224 + 6144 + wave * 512]);
    __syncthreads();

    for (int kb = 0; kb < kIters; ++kb) {  // kIters = 32
      const int nxt = cur ^ BUF;
      const bool pre = (kb + 1 < kIters);
      const int ko = (kb + 1) * 32;
      if (pre) {
        llds16(pB0g + ko, &lds[nxt + 4224 + wave * 512]);
        llds16(pB0g + 524288 + ko, &lds[nxt + 4224 + 2048 + wave * 512]);
        llds16(pB0g + 1048576 + ko, &lds[nxt + 4224 + 4096 + wave * 512]);
        llds16(pB3g + ko, &lds[nxt + 4224 + 6144 + wave * 512]);
        vA0 = *(const u16x8*)(pA0g + ko);
        vA1 = *(const u16x8*)(pA1g + ko);
        if (tid < 8) vAx = *(const u16x8*)(pAxg + ko);
        if (z0) vA0 = (u16x8){0, 0, 0, 0, 0, 0, 0, 0};
      }
      // A-frags: tap sh reads lds rows (output_row + sh); up == sh=2
      bf16x8 af00 = *(const bf16x8*)&lds[cur + (wave * 32 + 0 + l16) * 32 + quad * 8];
      bf16x8 af01 = *(const bf16x8*)&lds[cur + (wave * 32 + 1 + l16) * 32 + quad * 8];
      bf16x8 af02 = *(const bf16x8*)&lds[cur + (wave * 32 + 2 + l16) * 32 + quad * 8];
      bf16x8 af10 = *(const bf16x8*)&lds[cur + (wave * 32 + 16 + l16) * 32 + quad * 8];
      bf16x8 af11 = *(const bf16x8*)&lds[cur + (wave * 32 + 17 + l16) * 32 + quad * 8];
      bf16x8 af12 = *(const bf16x8*)&lds[cur + (wave * 32 + 18 + l16) * 32 + quad * 8];
      __builtin_amdgcn_s_setprio(1);
#pragma unroll
      for (int n = 0; n < 4; ++n) {
        bf16x8 b0 = *(const bf16x8*)&lds[cur + 4224 + (n * 16 + l16) * 32 + quad * 8];
        acc[0][n] = __builtin_amdgcn_mfma_f32_16x16x32_bf16(af00, b0, acc[0][n], 0, 0, 0);
        acc[1][n] = __builtin_amdgcn_mfma_f32_16x16x32_bf16(af10, b0, acc[1][n], 0, 0, 0);
        bf16x8 b1 = *(const bf16x8*)&lds[cur + 4224 + 2048 + (n * 16 + l16) * 32 + quad * 8];
        acc[0][n] = __builtin_amdgcn_mfma_f32_16x16x32_bf16(af01, b1, acc[0][n], 0, 0, 0);
        acc[1][n] = __builtin_amdgcn_mfma_f32_16x16x32_bf16(af11, b1, acc[1][n], 0, 0, 0);
        bf16x8 b2 = *(const bf16x8*)&lds[cur + 4224 + 4096 + (n * 16 + l16) * 32 + quad * 8];
        acc[0][n] = __builtin_amdgcn_mfma_f32_16x16x32_bf16(af02, b2, acc[0][n], 0, 0, 0);
        acc[1][n] = __builtin_amdgcn_mfma_f32_16x16x32_bf16(af12, b2, acc[1][n], 0, 0, 0);
        bf16x8 b3 = *(const bf16x8*)&lds[cur + 4224 + 6144 + (n * 16 + l16) * 32 + quad * 8];
        acc2[0][n] = __builtin_amdgcn_mfma_f32_16x16x32_bf16(af02, b3, acc2[0][n], 0, 0, 0);
        acc2[1][n] = __builtin_amdgcn_mfma_f32_16x16x32_bf16(af12, b3, acc2[1][n], 0, 0, 0);
      }
      __builtin_amdgcn_s_setprio(0);
      if (pre) {
        *(u16x8*)&lds[nxt + rowA0 * 32 + q8] = vA0;
        *(u16x8*)&lds[nxt + rowA1 * 32 + q8] = vA1;
        if (tid < 8) *(u16x8*)&lds[nxt + rowAx * 32 + q8] = vAx;
      }
      __syncthreads();
      cur = nxt;
    }
  }

  // ---- epilogue ----
  const int rbase = wave * 32;
  if constexpr (V == 0) {
#pragma unroll
    for (int mt = 0; mt < 2; ++mt)
#pragma unroll
      for (int r = 0; r < 4; ++r) {
        const int row = rbase + mt * 16 + quad * 4 + r;
#pragma unroll
        for (int nt = 0; nt < 4; ++nt) {
          float g = acc[mt][nt][r], u = acc[mt][nt + 4][r];
          float sg = g / (1.f + __expf(-g));
          lds[row * 64 + nt * 16 + l16] = f2bf(sg * u);
        }
      }
    __syncthreads();
#pragma unroll
    for (int i = 0; i < 4; ++i) {
      const int c = i * 256 + tid;
      const int row = c >> 3, s8 = (c & 7) * 8;
      const int slot = row0 + row;
      if (slot < row_end)
        *(u16x8*)(OUT + (long)slot * ldOut + n0 + s8) = *(const u16x8*)&lds[row * 64 + s8];
    }
  } else if constexpr (V == 1) {
#pragma unroll
    for (int mt = 0; mt < 2; ++mt)
#pragma unroll
      for (int r = 0; r < 4; ++r) {
        const int row = rbase + mt * 16 + quad * 4 + r;
        const float wgt = tok_w[min(row0 + row, row_end - 1)];
#pragma unroll
        for (int nt = 0; nt < 8; ++nt)
          lds[row * 128 + nt * 16 + l16] = f2bf(acc[mt][nt][r] * wgt);
      }
    __syncthreads();
#pragma unroll
    for (int i = 0; i < 8; ++i) {
      const int c = i * 256 + tid;
      const int row = c >> 4, s8 = (c & 15) * 8;
      const int slot = row0 + row;
      if (slot < row_end)
        *(u16x8*)(OUT + (long)slot * ldOut + n0 + s8) = *(const u16x8*)&lds[row * 128 + s8];
    }
  } else if constexpr (V == 3) {  // silu(conv) * up -> OUT (128 x 64 bf16)
#pragma unroll
    for (int mt = 0; mt < 2; ++mt)
#pragma unroll
      for (int r = 0; r < 4; ++r) {
        const int row = rbase + mt * 16 + quad * 4 + r;
#pragma unroll
        for (int n = 0; n < 4; ++n) {
          float g = acc[mt][n][r], u = acc2[mt][n][r];
          lds[row * 64 + n * 16 + l16] = f2bf(g / (1.f + __expf(-g)) * u);
        }
      }
    __syncthreads();
#pragma unroll
    for (int i = 0; i < 4; ++i) {
      const int c = i * 256 + tid;
      const int row = c >> 3, s8 = (c & 7) * 8;
      *(u16x8*)(OUT + (long)(row0 + row) * ldOut + n0 + s8) = *(const u16x8*)&lds[row * 64 + s8];
    }
  } else {  // V == 4: fused final combine, LDS-staged for coalescing
    // params repurposed: Bt1 = Y (bf16), tbl = slot_map, tok_w = topk_w,
    // tok_ids = (const int*)x (fp32 input)
    const u16* Yb = Bt1;
    const float* xf = (const float*)tok_ids;
    float* ldsF = (float*)lds;  // 64 rows x 128 cols fp32 = 32 KB
#pragma unroll
    for (int p = 0; p < 2; ++p) {
      if (p) __syncthreads();  // pass-0 reads done before overwrite
      if ((wave >> 1) == p) {
        const int lw = wave & 1;
#pragma unroll
        for (int mt = 0; mt < 2; ++mt)
#pragma unroll
          for (int r = 0; r < 4; ++r) {
            const int lrow = lw * 32 + mt * 16 + quad * 4 + r;
#pragma unroll
            for (int nt = 0; nt < 8; ++nt)
              ldsF[lrow * 128 + nt * 16 + l16] = acc[mt][nt][r];
          }
      }
      __syncthreads();
      // combine: 32 consecutive lanes sweep one row (f32x4 chunks) -> coalesced
#pragma unroll
      for (int i = 0; i < 8; ++i) {
        const int c = i * 256 + tid;
        const int lrow = c >> 5, c4 = (c & 31) * 4;
        const int grow = row0 + p * 64 + lrow;
        f32x4 o = *(const f32x4*)&ldsF[lrow * 128 + c4];
        const int sm0 = tbl[grow * 2], sm1 = tbl[grow * 2 + 1];
#pragma unroll
        for (int k2 = 0; k2 < 2; ++k2) {
          const int sm = k2 ? sm1 : sm0;
          if (sm >= 0) {
            u16x4 y = *(const u16x4*)(Yb + (long)sm * 1024 + n0 + c4);
#pragma unroll
            for (int j = 0; j < 4; ++j) o[j] += bf2f(y[j]);
          } else {
            const float w = tok_w[grow * 2 + k2];
            f32x4 xv = *(const f32x4*)(xf + (long)grow * 1024 + n0 + c4);
#pragma unroll
            for (int j = 0; j < 4; ++j) o[j] += w * xv[j];
          }
        }
        *(f32x4*)(OUTF + (long)grow * ldOut + n0 + c4) = o;
      }
    }
  }
}

extern "C" void kernel_launch(void* const* d_in, const int* in_sizes, int n_in,
                              void* d_out, int out_size, void* d_ws, size_t ws_size,
                              hipStream_t stream) {
  (void)in_sizes; (void)n_in; (void)out_size; (void)ws_size;
  const float* x   = (const float*)d_in[0];
  const float* rw  = (const float*)d_in[1];
  const float* rb  = (const float*)d_in[2];
  const float* gw  = (const float*)d_in[3];
  const float* uw  = (const float*)d_in[4];
  const float* dw  = (const float*)d_in[5];
  const float* cw  = (const float*)d_in[6];
  const float* suw = (const float*)d_in[7];
  const float* sdw = (const float*)d_in[8];
  float* out = (float*)d_out;

  char* base = (char*)d_ws;
  size_t off = 0;
  auto alloc = [&](size_t b) { void* p = base + off; off = (off + b + 255) & ~(size_t)255; return p; };
  u16* xb     = (u16*)alloc(16777216ull * 2);
  u16* gate_t = (u16*)alloc(15ull * 512 * 1024 * 2);
  u16* up_t   = (u16*)alloc(15ull * 512 * 1024 * 2);
  u16* down_t = (u16*)alloc(15ull * 1024 * 512 * 2);
  u16* conv_t = (u16*)alloc(3ull * 512 * 1024 * 2);
  u16* sup_t  = (u16*)alloc(512ull * 1024 * 2);
  u16* sdn_t  = (u16*)alloc(512ull * 1024 * 2);
  u16* inter  = (u16*)alloc(32768ull * 512 * 2);
  u16* Y      = (u16*)alloc(32768ull * 1024 * 2);
  u16* UP     = (u16*)alloc(16384ull * 512 * 2);
  int*   topi    = (int*)alloc(32768 * 4);
  float* topw    = (float*)alloc(32768 * 4);
  int*   smap    = (int*)alloc(32768 * 4);
  int*   tok_ids = (int*)alloc(32768 * 4);
  float* tokw    = (float*)alloc(32768 * 4);
  int*   ib      = (int*)alloc(8192);

  zero_k<<<1, 64, 0, stream>>>(ib);
  transpose_k<<<dim3(16, 32, 15), 256, 0, stream>>>(gw, gate_t, 1024, 512);
  transpose_k<<<dim3(16, 32, 15), 256, 0, stream>>>(uw, up_t, 1024, 512);
  transpose_k<<<dim3(32, 16, 15), 256, 0, stream>>>(dw, down_t, 512, 1024);
  transpose_k<<<dim3(16, 32, 1), 256, 0, stream>>>(suw, sup_t, 1024, 512);
  transpose_k<<<dim3(32, 16, 1), 256, 0, stream>>>(sdw, sdn_t, 512, 1024);
  convt_k<<<6144, 256, 0, stream>>>(cw, conv_t);
  router_k<<<256, 256, 0, stream>>>(x, rw, rb, topi, topw, ib, xb);  // + xb emit
  scan_k<<<1, 64, 0, stream>>>(ib);
  scatter_k<<<128, 256, 0, stream>>>(topi, topw, ib, tok_ids, tokw, smap);
  // routed experts (flat XCD-aware grids: 272*8, 272*8)
  gemm_k<0><<<2176, 256, 0, stream>>>(xb, gate_t, up_t, inter, ib + 64, ib + 48,
                                      tok_ids, tokw, 1024, 1024, 512);
  gemm_k<1><<<2176, 256, 0, stream>>>(inter, down_t, nullptr, Y, ib + 64, ib + 48,
                                      nullptr, tokw, 512, 512, 1024);
  // shared expert: single-pass fused conv-gate + up (flat: 128*8, 64-col tiles)
  gemm_k<3><<<1024, 256, 0, stream>>>(xb, conv_t, sup_t, UP, nullptr, nullptr,
                                      nullptr, nullptr, 1024, 1024, 512);
  // shared-down + fused final combine (flat: 128*8)
  gemm_k<4><<<1024, 256, 0, stream>>>(UP, sdn_t, Y, out, smap, nullptr,
                                      (const int*)x, topw, 512, 512, 1024);
}